// Round 1
// baseline (2585.372 us; speedup 1.0000x reference)
//
#include <hip/hip_runtime.h>
#include <hip/hip_bf16.h>

// Problem: B=8,H=256,W=256,C=256. pairs = B*H = 2048.
// out[b,h,i,d] = gamma[d]*O + x ; O = softmax_j(Q K^T) V
// Trick: QK^T row-softmax == softmax of (X M X^T + (u.x_j)) with M = Wq Wk^T, u = Wk bq
//        (terms constant along j drop out of softmax). O = A V, V = X Wv + bv.
// Kernel 2: per pair, X(bf16) in LDS; Y=X*M, S^T=X*Y'^T, softmax -> A bf16 parked in
//           upper half of this pair's own 256KB d_out slot (no cross-block hazards).
// Kernel 3: per pair, V^T in LDS; O = A*V with A prefetched to regs; epilogue writes
//           fp32 out over the slot with a schedule that never clobbers unread A.

#define NPAIR 2048
#define SEQ 256     // W
#define DIM 256     // C
#define XSTR 264    // LDS row stride in bf16 elems (528 B, 16B-aligned, bank-spread)
#define SCRSTR 48   // per-wave Y' scratch row stride (96 B, 16B-aligned)

typedef __attribute__((ext_vector_type(8))) short bf16x8;
typedef __attribute__((ext_vector_type(4))) float f32x4;

__device__ __forceinline__ unsigned short f2bf(float f) {
  union { float f; unsigned u; } v; v.f = f;
  unsigned r = v.u + 0x7FFFu + ((v.u >> 16) & 1u);   // round-to-nearest-even
  return (unsigned short)(r >> 16);
}

// ---------------- prep: MT = (Wq Wk^T)^T (bf16), u = Wk bq (f32), WvT = Wv^T (bf16)
__global__ void prep_kernel(const float* __restrict__ wq, const float* __restrict__ bq,
                            const float* __restrict__ wk, const float* __restrict__ wv,
                            unsigned short* __restrict__ MT, unsigned short* __restrict__ WvT,
                            float* __restrict__ u) {
  int b = blockIdx.x, t = threadIdx.x;
  if (b < 256) {
    int r = b;  // MT[r][c] = sum_d wq[c][d]*wk[r][d]  == M[c][r]
    for (int c = t; c < 256; c += blockDim.x) {
      float acc = 0.f;
      for (int d = 0; d < 256; ++d) acc += wq[c * 256 + d] * wk[r * 256 + d];
      MT[r * 256 + c] = f2bf(acc);
    }
  } else if (b == 256) {
    for (int cc = t; cc < 256; cc += blockDim.x) {
      float acc = 0.f;
      for (int d = 0; d < 256; ++d) acc += wk[cc * 256 + d] * bq[d];
      u[cc] = acc;
    }
  } else {
    int r = b - 257;  // WvT[r][c] = wv[c][r]
    for (int c = t; c < 256; c += blockDim.x) WvT[r * 256 + c] = f2bf(wv[c * 256 + r]);
  }
}

// ---------------- kernel 2: scores. grid=2048, block=512 (8 waves)
__global__ __launch_bounds__(512, 2)
void attn_scores_kernel(const float* __restrict__ x, const unsigned short* __restrict__ MT,
                        const float* __restrict__ u, float* __restrict__ out) {
  __shared__ unsigned short Xs[SEQ * XSTR];            // 135168 B, X[j][c] bf16
  __shared__ unsigned short Yscr[8][16 * SCRSTR];      // 12288 B, per-wave Y' eighth
  const int p = blockIdx.x;
  const long xbase = (long)p * (SEQ * DIM);
  const int tid = threadIdx.x;
  const int wid = tid >> 6;
  const int ln = tid & 63;
  const int l16 = ln & 15;
  const int quad = ln >> 4;

  // stage X -> LDS bf16 (pairs, coalesced)
  for (int it = 0; it < 64; ++it) {
    int idx = 2 * (tid + 512 * it);
    float2 v = *(const float2*)(x + xbase + idx);
    int j = idx >> 8, c = idx & 255;
    unsigned pack = (unsigned)f2bf(v.x) | ((unsigned)f2bf(v.y) << 16);
    *(unsigned*)&Xs[j * XSTR + c] = pack;
  }
  __syncthreads();

  float ureg[16];
#pragma unroll
  for (int nt = 0; nt < 16; ++nt) ureg[nt] = u[nt * 16 + l16];

  unsigned short* Aout =
      (unsigned short*)((char*)out + (size_t)p * (SEQ * DIM * 4) + 131072);
  unsigned short* scr = &Yscr[wid][0];

  for (int ch = 0; ch < 2; ++ch) {
    const int chunk = wid + 8 * ch;   // i-chunk 0..15 (16 q-rows each)
    const int i0 = chunk * 16;

    // ---- Y[i][d] = sum_c X[i][c] M[c][d]   (m=i, n=d, k=c)
    f32x4 acc[16];
#pragma unroll
    for (int nt = 0; nt < 16; ++nt) acc[nt] = (f32x4){0.f, 0.f, 0.f, 0.f};
#pragma unroll
    for (int ks = 0; ks < 8; ++ks) {
      bf16x8 a = *(const bf16x8*)&Xs[(i0 + l16) * XSTR + ks * 32 + quad * 8];
#pragma unroll
      for (int nt = 0; nt < 16; ++nt) {
        bf16x8 b = *(const bf16x8*)&MT[(nt * 16 + l16) * 256 + ks * 32 + quad * 8];
        acc[nt] = __builtin_amdgcn_mfma_f32_16x16x32_bf16(a, b, acc[nt], 0, 0, 0);
      }
    }

    // ---- S^T[j][ii] = sum_d X[j][d] * Y'[i0+ii][d]   (m=j, n=ii, k=d), by d-eighths
    f32x4 sacc[16];
#pragma unroll
    for (int mt = 0; mt < 16; ++mt) sacc[mt] = (f32x4){0.f, 0.f, 0.f, 0.f};
#pragma unroll
    for (int e = 0; e < 8; ++e) {
      asm volatile("s_waitcnt lgkmcnt(0)" ::: "memory");
#pragma unroll
      for (int h = 0; h < 2; ++h) {
        int nt = 2 * e + h;
#pragma unroll
        for (int r = 0; r < 4; ++r) {
          float yv = acc[nt][r] + ureg[nt];
          scr[(quad * 4 + r) * SCRSTR + h * 16 + l16] = f2bf(yv);
        }
      }
      asm volatile("s_waitcnt lgkmcnt(0)" ::: "memory");
      bf16x8 bfrag = *(const bf16x8*)&scr[l16 * SCRSTR + quad * 8];
#pragma unroll
      for (int mt = 0; mt < 16; ++mt) {
        bf16x8 a = *(const bf16x8*)&Xs[(mt * 16 + l16) * XSTR + e * 32 + quad * 8];
        sacc[mt] = __builtin_amdgcn_mfma_f32_16x16x32_bf16(a, bfrag, sacc[mt], 0, 0, 0);
      }
    }

    // ---- softmax over j for row ii=l16 (lane holds j = mt*16 + quad*4 + r)
    float mx = -1e30f;
#pragma unroll
    for (int mt = 0; mt < 16; ++mt)
#pragma unroll
      for (int r = 0; r < 4; ++r) mx = fmaxf(mx, sacc[mt][r]);
    mx = fmaxf(mx, __shfl_xor(mx, 16, 64));
    mx = fmaxf(mx, __shfl_xor(mx, 32, 64));
    float sum = 0.f;
#pragma unroll
    for (int mt = 0; mt < 16; ++mt)
#pragma unroll
      for (int r = 0; r < 4; ++r) {
        float ev = exp2f((sacc[mt][r] - mx) * 1.44269504088896340736f);
        sacc[mt][r] = ev;
        sum += ev;
      }
    sum += __shfl_xor(sum, 16, 64);
    sum += __shfl_xor(sum, 32, 64);
    float rs = 1.0f / sum;

    // ---- write A[i][j] bf16 into upper half of own out slot
#pragma unroll
    for (int mt = 0; mt < 16; ++mt)
#pragma unroll
      for (int r = 0; r < 4; ++r) {
        int j = mt * 16 + quad * 4 + r;
        Aout[(i0 + l16) * 256 + j] = f2bf(sacc[mt][r] * rs);
      }
  }
}

// ---------------- kernel 3: V^T in LDS, O = A*V, epilogue. grid=2048, block=512
__global__ __launch_bounds__(512, 2)
void attn_out_kernel(const float* __restrict__ x, const unsigned short* __restrict__ WvT,
                     const float* __restrict__ bv, const float* __restrict__ gamma,
                     float* __restrict__ out) {
  __shared__ unsigned short Vs[DIM * XSTR];  // V^T[d][j] bf16, 135168 B
  const int p = blockIdx.x;
  const long xbase = (long)p * (SEQ * DIM);
  const int tid = threadIdx.x;
  const int wid = tid >> 6;
  const int ln = tid & 63;
  const int l16 = ln & 15;
  const int quad = ln >> 4;
  unsigned short* Aslot =
      (unsigned short*)((char*)out + (size_t)p * (SEQ * DIM * 4) + 131072);

  // prefetch A rows for chunk0 = wid (in flight during phase 1)
  bf16x8 afr[8];
  {
    int i = 16 * wid + l16;
#pragma unroll
    for (int ks = 0; ks < 8; ++ks)
      afr[ks] = *(const bf16x8*)&Aslot[i * 256 + ks * 32 + quad * 8];
  }

  // ---- phase 1: V^T[d][j] = sum_c WvT[d][c] X[j][c] + bv[d]; wave: j in [32*wid, +32)
  {
    f32x4 vacc[16][2];
#pragma unroll
    for (int mt = 0; mt < 16; ++mt) {
      vacc[mt][0] = (f32x4){0.f, 0.f, 0.f, 0.f};
      vacc[mt][1] = (f32x4){0.f, 0.f, 0.f, 0.f};
    }
#pragma unroll
    for (int ks = 0; ks < 8; ++ks) {
      bf16x8 bfr[2];
#pragma unroll
      for (int nt = 0; nt < 2; ++nt) {
        const float* xp = x + xbase + (long)(32 * wid + nt * 16 + l16) * 256 + ks * 32 + quad * 8;
        float4 x0 = *(const float4*)xp;
        float4 x1 = *(const float4*)(xp + 4);
        union { bf16x8 v; unsigned short s[8]; } uu;
        uu.s[0] = f2bf(x0.x); uu.s[1] = f2bf(x0.y); uu.s[2] = f2bf(x0.z); uu.s[3] = f2bf(x0.w);
        uu.s[4] = f2bf(x1.x); uu.s[5] = f2bf(x1.y); uu.s[6] = f2bf(x1.z); uu.s[7] = f2bf(x1.w);
        bfr[nt] = uu.v;
      }
#pragma unroll
      for (int mt = 0; mt < 16; ++mt) {
        bf16x8 a = *(const bf16x8*)&WvT[(mt * 16 + l16) * 256 + ks * 32 + quad * 8];
        vacc[mt][0] = __builtin_amdgcn_mfma_f32_16x16x32_bf16(a, bfr[0], vacc[mt][0], 0, 0, 0);
        vacc[mt][1] = __builtin_amdgcn_mfma_f32_16x16x32_bf16(a, bfr[1], vacc[mt][1], 0, 0, 0);
      }
    }
#pragma unroll
    for (int mt = 0; mt < 16; ++mt)
#pragma unroll
      for (int r = 0; r < 4; ++r) {
        int d = mt * 16 + quad * 4 + r;
        float bvv = bv[d];
#pragma unroll
        for (int nt = 0; nt < 2; ++nt) {
          int j = 32 * wid + nt * 16 + l16;
          Vs[d * XSTR + j] = f2bf(vacc[mt][nt][r] + bvv);
        }
      }
  }
  float greg[16];
#pragma unroll
  for (int nt = 0; nt < 16; ++nt) greg[nt] = gamma[nt * 16 + l16];
  __syncthreads();

  // ---- phase 2: O[i][dd] = sum_j A[i][j] V^T[dd][j]  (m=i, n=dd, k=j)
  float* outp = out + (size_t)p * (SEQ * DIM);
  for (int rnd = 0; rnd < 2; ++rnd) {
    const int i0 = (wid + 8 * rnd) * 16;
    f32x4 oacc[16];
#pragma unroll
    for (int nt = 0; nt < 16; ++nt) oacc[nt] = (f32x4){0.f, 0.f, 0.f, 0.f};
#pragma unroll
    for (int ks = 0; ks < 8; ++ks) {
      bf16x8 a = afr[ks];
#pragma unroll
      for (int nt = 0; nt < 16; ++nt) {
        bf16x8 b = *(const bf16x8*)&Vs[(nt * 16 + l16) * XSTR + ks * 32 + quad * 8];
        oacc[nt] = __builtin_amdgcn_mfma_f32_16x16x32_bf16(a, b, oacc[nt], 0, 0, 0);
      }
    }
    if (rnd == 0) {
      // prefetch A for chunk 8+wid; barrier guarantees all waves' A is in regs
      // before any round-1 out-store can clobber the A region (bytes >= 128K).
      int i = 16 * (8 + wid) + l16;
#pragma unroll
      for (int ks = 0; ks < 8; ++ks)
        afr[ks] = *(const bf16x8*)&Aslot[i * 256 + ks * 32 + quad * 8];
      asm volatile("s_waitcnt vmcnt(0)" ::: "memory");
      __syncthreads();
    }
    // epilogue: round-0 rows < 128 -> below A region; round-1 free to clobber.
#pragma unroll
    for (int nt = 0; nt < 16; ++nt)
#pragma unroll
      for (int r = 0; r < 4; ++r) {
        int i = i0 + quad * 4 + r;
        int dd = nt * 16 + l16;
        float xv = x[xbase + (long)i * 256 + dd];
        outp[(long)i * 256 + dd] = greg[nt] * oacc[nt][r] + xv;
      }
  }
}

extern "C" void kernel_launch(void* const* d_in, const int* in_sizes, int n_in,
                              void* d_out, int out_size, void* d_ws, size_t ws_size,
                              hipStream_t stream) {
  const float* x     = (const float*)d_in[0];
  const float* wq    = (const float*)d_in[1];
  const float* bq    = (const float*)d_in[2];
  const float* wk    = (const float*)d_in[3];
  // d_in[4] = bk: row-constant in softmax logits -> drops out, unused.
  const float* wv    = (const float*)d_in[5];
  const float* bv    = (const float*)d_in[6];
  const float* gamma = (const float*)d_in[7];
  float* out = (float*)d_out;

  unsigned short* MT  = (unsigned short*)d_ws;   // 131072 B
  unsigned short* WvT = MT + 65536;              // 131072 B
  float* u            = (float*)(WvT + 65536);   // 1024 B   (total 263168 B of ws)

  prep_kernel<<<513, 256, 0, stream>>>(wq, bq, wk, wv, MT, WvT, u);
  attn_scores_kernel<<<NPAIR, 512, 0, stream>>>(x, MT, u, out);
  attn_out_kernel<<<NPAIR, 512, 0, stream>>>(x, WvT, bv, gamma, out);
}